// Round 3
// baseline (389.011 us; speedup 1.0000x reference)
//
#include <hip/hip_runtime.h>

// OverlapCalculator: pairwise IoU [50000 x 2000] fp32, row max + argmax.
// Outputs (flat fp32): pred_bbox[200000] | gt_bbox[8000] | max[50000] | argmax-as-float[50000]
//
// Two-phase design:
//  Phase 1 (hot, ~99% of FLOPs): per (pred, chunk-of-125-gts) compute an
//    approximate chunk max WITHOUT divides/branches/argmax. Running max kept
//    as a cross-multiplied pair (bi,bu): new wins iff inter*bu > bi*uni
//    (true-rational compare up to ~1.2e-7 product rounding). Chunk result
//    stored as fl(bi/bu) -- an exact fl-quotient of a real candidate pair.
//  Phase 2 (tiny): per pred, threshold t = max_c amax_c * (1-1e-5). Any
//    chunk whose max fl-quotient could be >= the global max satisfies
//    amax_c >= t  (worst-case approx error ~7e-7 << 1e-5), so pruned chunks
//    provably contain no argmax. Surviving chunks (~1) are rescanned in
//    ascending j with EXACT semantics: same op order as np ref
//    (uni=(ap+ag)-inter, fp contract off), sound skip-filter
//    inter > fl(fl(best*K)*uni), K=1-3.6e-7  (skip => fl(inter/uni) < best),
//    IEEE divide + strict '>' on the taken path => bit-exact max and
//    first-occurrence argmax (ascending chunks, strict '>').

#define N_PRED 50000
#define N_GT   2000
#define CHUNKS 16
#define CHUNK  125          // N_GT / CHUNKS
#define BLOCK  256
#define KFILT  0.99999964f  // 1 - 3.6e-7  (sound skip filter)
#define TMARG  0.99999f     // 1 - 1e-5    (chunk prune margin, ~14x slack)

// --- setup: precompute gt areas (same fl expression as ref) -----------------
__global__ __launch_bounds__(BLOCK) void gt_areas_kernel(
        const float4* __restrict__ gt, float* __restrict__ areas) {
#pragma clang fp contract(off)
    int j = blockIdx.x * BLOCK + threadIdx.x;
    if (j < N_GT) {
        float4 g = gt[j];
        areas[j] = (g.z - g.x) * (g.w - g.y);
    }
}

// --- phase 1: grid (98, 16); 2 preds per thread; branchless, divide-free ----
__global__ __launch_bounds__(BLOCK) void chunk_max(
        const float4* __restrict__ pred, const float4* __restrict__ gt,
        const float* __restrict__ areas, float* __restrict__ ws_amax) {
    const int c    = blockIdx.y;
    const int base = c * CHUNK;
    const int i0   = blockIdx.x * (BLOCK * 2) + threadIdx.x;
    const int i1   = i0 + BLOCK;

    const float4 p0 = pred[i0 < N_PRED ? i0 : N_PRED - 1];
    const float4 p1 = pred[i1 < N_PRED ? i1 : N_PRED - 1];
    const float ap0 = (p0.z - p0.x) * (p0.w - p0.y);
    const float ap1 = (p1.z - p1.x) * (p1.w - p1.y);

    float bi0 = 0.0f, bu0 = 1.0f;   // best (inter, union) pair, pred0
    float bi1 = 0.0f, bu1 = 1.0f;   // best pair, pred1

#pragma unroll 5
    for (int j = 0; j < CHUNK; ++j) {
        // wave-uniform index -> scalar loads (broadcast), no LDS pipe
        const float4 g  = gt[base + j];
        const float  ag = areas[base + j];

        float w0 = fmaxf(fminf(p0.z, g.z) - fmaxf(p0.x, g.x), 0.0f);
        float h0 = fmaxf(fminf(p0.w, g.w) - fmaxf(p0.y, g.y), 0.0f);
        float in0 = w0 * h0;
        float un0 = (ap0 + ag) - in0;
        bool m0 = in0 * bu0 > bi0 * un0;     // true-rational compare
        bi0 = m0 ? in0 : bi0;
        bu0 = m0 ? un0 : bu0;

        float w1 = fmaxf(fminf(p1.z, g.z) - fmaxf(p1.x, g.x), 0.0f);
        float h1 = fmaxf(fminf(p1.w, g.w) - fmaxf(p1.y, g.y), 0.0f);
        float in1 = w1 * h1;
        float un1 = (ap1 + ag) - in1;
        bool m1 = in1 * bu1 > bi1 * un1;
        bi1 = m1 ? in1 : bi1;
        bu1 = m1 ? un1 : bu1;
    }
    if (i0 < N_PRED) ws_amax[c * N_PRED + i0] = bi0 / bu0;  // exact fl-quotient
    if (i1 < N_PRED) ws_amax[c * N_PRED + i1] = bi1 / bu1;
}

// --- phase 2: prune chunks, exact rescan per lane, fused passthrough --------
__global__ __launch_bounds__(BLOCK) void resolve_copy(
        const float* __restrict__ ws_amax,
        const float4* __restrict__ pred, const float4* __restrict__ gt,
        const float* __restrict__ areas, float* __restrict__ out) {
#pragma clang fp contract(off)
    const int i = blockIdx.x * BLOCK + threadIdx.x;
    float4* out_pred = (float4*)out;                    // 50000 float4
    float4* out_gt   = (float4*)(out + 4 * N_PRED);     // 2000 float4
    float*  out_max  = out + 4 * N_PRED + 4 * N_GT;     // 50000
    float*  out_idx  = out_max + N_PRED;                // 50000

    if (i < N_GT) out_gt[i] = gt[i];
    const bool valid = i < N_PRED;
    const int  ii    = valid ? i : 0;
    if (valid) out_pred[i] = pred[i];

    const float4 p  = pred[ii];
    const float  ap = (p.z - p.x) * (p.w - p.y);

    // threshold from chunk maxima
    float amax = 0.0f;
    float am[CHUNKS];
#pragma unroll
    for (int c = 0; c < CHUNKS; ++c) {
        am[c] = ws_amax[c * N_PRED + ii];
        amax  = fmaxf(amax, am[c]);
    }
    const float t = amax * TMARG;
    unsigned cmask = 0;
#pragma unroll
    for (int c = 0; c < CHUNKS; ++c)
        if (am[c] >= t) cmask |= (1u << c);
    if (!valid) cmask = 0;

    float best = -1.0f;     // first taken candidate always divides once
    float tb   = -KFILT;    // best * KFILT
    int   bidx = 0;

    // each lane walks ITS candidate chunks, ascending (first-occurrence safe)
    while (__any(cmask != 0)) {
        const bool has = (cmask != 0);
        const int  c   = has ? __builtin_ctz(cmask) : 0;
        if (has) cmask &= cmask - 1;
        const int cb = c * CHUNK;
        for (int j = 0; j < CHUNK; ++j) {
            const float4 g  = gt[cb + j];       // per-lane load, gt is L1-hot
            const float  ag = areas[cb + j];
            float w  = fmaxf(fminf(p.z, g.z) - fmaxf(p.x, g.x), 0.0f);
            float h  = fmaxf(fminf(p.w, g.w) - fmaxf(p.y, g.y), 0.0f);
            float in = w * h;
            float un = (ap + ag) - in;          // same assoc order as ref
            if (has && in > tb * un) {          // sound skip filter
                float q = in / un;              // exact IEEE divide (rare)
                if (q > best) { best = q; tb = best * KFILT; bidx = cb + j; }
            }
        }
    }
    if (valid) { out_max[i] = best; out_idx[i] = (float)bidx; }
}

extern "C" void kernel_launch(void* const* d_in, const int* in_sizes, int n_in,
                              void* d_out, int out_size, void* d_ws, size_t ws_size,
                              hipStream_t stream) {
    const float4* pred = (const float4*)d_in[0];
    const float4* gt   = (const float4*)d_in[1];
    float* out = (float*)d_out;

    // ws: areas[2048] | amax[16*50000]  (~3.2 MB)
    float* areas   = (float*)d_ws;
    float* ws_amax = areas + 2048;

    gt_areas_kernel<<<dim3((N_GT + BLOCK - 1) / BLOCK), BLOCK, 0, stream>>>(gt, areas);
    chunk_max<<<dim3((N_PRED + 2 * BLOCK - 1) / (2 * BLOCK), CHUNKS), BLOCK, 0, stream>>>(
        pred, gt, areas, ws_amax);
    resolve_copy<<<dim3((N_PRED + BLOCK - 1) / BLOCK), BLOCK, 0, stream>>>(
        ws_amax, pred, gt, areas, out);
}

// Round 4
// 318.028 us; speedup vs baseline: 1.2232x; 1.2232x over previous
//
#include <hip/hip_runtime.h>

// OverlapCalculator: pairwise IoU [50000 x 2000] fp32, row max + argmax.
// Outputs (flat fp32): pred_bbox[200000] | gt_bbox[8000] | max[50000] | argmax-as-float[50000]
//
// Two-phase, bit-exact:
//  Phase 1 (hot): per (pred, 125-gt chunk) approx max, branchless/divide-free,
//    running max as cross-multiplied pair (bi,bu): win iff in*bu > bi*un.
//    gt chunk in LDS (broadcast reads), 4 preds/thread to amortize loads.
//    Chunk result A_c = fl(bi/bu): an exact fl-quotient of a real pair, so
//    A_c <= M_c (true chunk max of fl-quotients). Downward drift: each of
//    <=125 compares errs only on rel-ties < ~1.2e-7 => A_c >= M_c*(1-2e-5).
//  Phase 2: amax = max_c A_c; keep chunks with A_c >= amax*(1-1e-4) (5x slack
//    over the 2e-5 drift bound => every chunk containing a global-max
//    attainer survives). All gts in LDS (40 KB). Surviving chunks rescanned
//    ascending with EXACT ref semantics: un=(ap+ag)-in, fp contract off,
//    sound skip filter in > fl(fl(best*K)*un), K=1-3.6e-7 (skip =>
//    fl(in/un) < best), IEEE divide + strict '>' => bit-exact max and
//    first-occurrence argmax.

#define N_PRED 50000
#define N_GT   2000
#define CHUNKS 16
#define CHUNK  125
#define BLOCK  256
#define PPT    4                 // preds per thread in phase 1
#define KFILT  0.99999964f       // 1 - 3.6e-7 (sound skip filter)
#define TMARG  0.9999f           // 1 - 1e-4   (chunk prune margin)

// --- phase 1: grid (49, 16) --------------------------------------------------
__global__ __launch_bounds__(BLOCK) void chunk_max(
        const float4* __restrict__ pred, const float4* __restrict__ gt,
        float* __restrict__ ws_amax) {
#pragma clang fp contract(off)
    __shared__ float4 sg[CHUNK];
    __shared__ float  sa[CHUNK];
    const int tid  = threadIdx.x;
    const int c    = blockIdx.y;
    const int base = c * CHUNK;
    if (tid < CHUNK) {
        float4 g = gt[base + tid];
        sg[tid] = g;
        sa[tid] = (g.z - g.x) * (g.w - g.y);   // same fl expr as ref
    }
    __syncthreads();

    int    idx[PPT];
    float4 p[PPT];
    float  ap[PPT], bi[PPT], bu[PPT];
#pragma unroll
    for (int k = 0; k < PPT; ++k) {
        int i  = blockIdx.x * (BLOCK * PPT) + k * BLOCK + tid;
        idx[k] = i;
        i      = i < N_PRED ? i : N_PRED - 1;
        p[k]   = pred[i];
        ap[k]  = (p[k].z - p[k].x) * (p[k].w - p[k].y);
        bi[k]  = 0.0f;
        bu[k]  = 1.0f;
    }

#pragma unroll 5
    for (int j = 0; j < CHUNK; ++j) {
        const float4 g  = sg[j];   // wave-uniform -> broadcast, conflict-free
        const float  ag = sa[j];
#pragma unroll
        for (int k = 0; k < PPT; ++k) {
            float w  = fmaxf(fminf(p[k].z, g.z) - fmaxf(p[k].x, g.x), 0.0f);
            float h  = fmaxf(fminf(p[k].w, g.w) - fmaxf(p[k].y, g.y), 0.0f);
            float in = w * h;
            float un = (ap[k] + ag) - in;
            bool  m  = in * bu[k] > bi[k] * un;   // true-rational compare
            bi[k] = m ? in : bi[k];
            bu[k] = m ? un : bu[k];
        }
    }
#pragma unroll
    for (int k = 0; k < PPT; ++k)
        if (idx[k] < N_PRED)
            ws_amax[c * N_PRED + idx[k]] = bi[k] / bu[k];
}

// --- phase 2: grid (196); all gts in LDS; prune + exact rescan + passthrough -
__global__ __launch_bounds__(BLOCK) void resolve_copy(
        const float* __restrict__ ws_amax,
        const float4* __restrict__ pred, const float4* __restrict__ gt,
        float* __restrict__ out) {
#pragma clang fp contract(off)
    __shared__ float4 sg[N_GT];   // 32 KB
    __shared__ float  sa[N_GT];   //  8 KB
    float4* out_pred = (float4*)out;                 // 50000 float4
    float4* out_gt   = (float4*)(out + 4 * N_PRED);  // 2000 float4
    float*  out_max  = out + 4 * N_PRED + 4 * N_GT;  // 50000
    float*  out_idx  = out_max + N_PRED;             // 50000

    for (int j = threadIdx.x; j < N_GT; j += BLOCK) {
        float4 g = gt[j];
        sg[j] = g;
        sa[j] = (g.z - g.x) * (g.w - g.y);
        if (blockIdx.x == 0) out_gt[j] = g;          // fused passthrough
    }
    __syncthreads();

    const int  i     = blockIdx.x * BLOCK + threadIdx.x;
    const bool valid = i < N_PRED;
    const int  ii    = valid ? i : 0;
    const float4 p   = pred[ii];
    if (valid) out_pred[i] = p;                      // fused passthrough
    const float ap = (p.z - p.x) * (p.w - p.y);

    float amax = 0.0f;
    float am[CHUNKS];
#pragma unroll
    for (int c = 0; c < CHUNKS; ++c) {
        am[c] = ws_amax[c * N_PRED + ii];            // coalesced
        amax  = fmaxf(amax, am[c]);
    }
    const float t = amax * TMARG;
    unsigned cmask = 0;
#pragma unroll
    for (int c = 0; c < CHUNKS; ++c)
        if (am[c] >= t) cmask |= (1u << c);
    if (!valid) cmask = 0;

    float best = -1.0f;     // first taken candidate divides exactly once
    float tb   = -KFILT;
    int   bidx = 0;

    while (__any(cmask != 0)) {
        const bool has = (cmask != 0);
        const int  c   = has ? __builtin_ctz(cmask) : 0;
        if (has) cmask &= cmask - 1;
        const int cb = c * CHUNK;
        for (int j = 0; j < CHUNK; ++j) {
            const float4 g  = sg[cb + j];            // LDS, divergent but fast
            const float  ag = sa[cb + j];
            float w  = fmaxf(fminf(p.z, g.z) - fmaxf(p.x, g.x), 0.0f);
            float h  = fmaxf(fminf(p.w, g.w) - fmaxf(p.y, g.y), 0.0f);
            float in = w * h;
            float un = (ap + ag) - in;               // same assoc order as ref
            if (has && in > tb * un) {               // sound skip filter
                float q = in / un;                   // exact IEEE divide (rare)
                if (q > best) { best = q; tb = best * KFILT; bidx = cb + j; }
            }
        }
    }
    if (valid) { out_max[i] = best; out_idx[i] = (float)bidx; }
}

extern "C" void kernel_launch(void* const* d_in, const int* in_sizes, int n_in,
                              void* d_out, int out_size, void* d_ws, size_t ws_size,
                              hipStream_t stream) {
    const float4* pred = (const float4*)d_in[0];
    const float4* gt   = (const float4*)d_in[1];
    float* out = (float*)d_out;

    float* ws_amax = (float*)d_ws;   // 16 * 50000 floats = 3.2 MB

    const int gx1 = (N_PRED + BLOCK * PPT - 1) / (BLOCK * PPT);  // 49
    chunk_max<<<dim3(gx1, CHUNKS), BLOCK, 0, stream>>>(pred, gt, ws_amax);

    const int gx2 = (N_PRED + BLOCK - 1) / BLOCK;                // 196
    resolve_copy<<<dim3(gx2), BLOCK, 0, stream>>>(ws_amax, pred, gt, out);
}

// Round 5
// 126.249 us; speedup vs baseline: 3.0813x; 2.5190x over previous
//
#include <hip/hip_runtime.h>

// OverlapCalculator: pairwise IoU [50000 x 2000] fp32, row max + argmax.
// Outputs (flat fp32): pred_bbox[200000] | gt_bbox[8000] | max[50000] | argmax-as-float[50000]
//
// Two-phase, bit-exact vs numpy fp32:
//  Phase 1 (hot): per (pred, 125-gt chunk) approximate chunk max, branchless,
//    divide-free. Running max as cross-multiplied pair (bi,bu): win iff
//    in*bu > bi*un (both denominators > 0). Each compare errs only on
//    relative ties < ~2.4e-7, so A_c = fl(bi/bu) satisfies
//    M_c*(1-3e-5) <= A_c <= M_c  (M_c = true chunk max of fl-quotients,
//    drift <= 125*2.4e-7). Stored pred-major: ws[i*16+c].
//  Phase 2 (wave per pred): amax = max_c A_c; chunks with A_c >= amax*(1-1e-4)
//    survive (3x slack over drift => every chunk containing a global-max
//    attainer survives; pruned chunks are provably strictly below the max).
//    Lanes scan surviving chunks' gts coalesced, compute the EXACT ref
//    expression per pair: w,h clip, in=w*h, un=(ap+ag)-in, q=in/un (IEEE
//    divide), fp contract off. Lexicographic (q, -idx) wave reduce =>
//    bit-exact max and numpy first-occurrence argmax.

#define N_PRED 50000
#define N_GT   2000
#define CHUNKS 16
#define CHUNK  125
#define BLOCK  256
#define PPT    2
#define TMARG  0.9999f    // 1 - 1e-4 chunk prune margin (drift bound 3e-5)

// --- phase 1: grid (98, 16); 2 preds/thread; gt chunk in LDS ----------------
__global__ __launch_bounds__(BLOCK) void chunk_max(
        const float4* __restrict__ pred, const float4* __restrict__ gt,
        float* __restrict__ ws_amax, float* __restrict__ out) {
#pragma clang fp contract(off)
    __shared__ float4 sg[CHUNK];
    const int tid  = threadIdx.x;
    const int c    = blockIdx.y;
    const int base = c * CHUNK;
    if (tid < CHUNK) sg[tid] = gt[base + tid];
    __syncthreads();

    const int idx0 = blockIdx.x * (BLOCK * PPT) + tid;
    const int idx1 = idx0 + BLOCK;
    const float4 p0 = pred[idx0 < N_PRED ? idx0 : N_PRED - 1];
    const float4 p1 = pred[idx1 < N_PRED ? idx1 : N_PRED - 1];
    const float ap0 = (p0.z - p0.x) * (p0.w - p0.y);
    const float ap1 = (p1.z - p1.x) * (p1.w - p1.y);

    float bi0 = 0.0f, bu0 = 1.0f;
    float bi1 = 0.0f, bu1 = 1.0f;

#pragma unroll 5
    for (int j = 0; j < CHUNK; ++j) {
        const float4 g  = sg[j];                      // uniform -> broadcast
        const float  ag = (g.z - g.x) * (g.w - g.y);  // recompute: LDS pipe off hot path

        float w0 = fmaxf(fminf(p0.z, g.z) - fmaxf(p0.x, g.x), 0.0f);
        float h0 = fmaxf(fminf(p0.w, g.w) - fmaxf(p0.y, g.y), 0.0f);
        float i0 = w0 * h0;
        float u0 = (ap0 + ag) - i0;
        bool  m0 = i0 * bu0 > bi0 * u0;
        bi0 = m0 ? i0 : bi0;
        bu0 = m0 ? u0 : bu0;

        float w1 = fmaxf(fminf(p1.z, g.z) - fmaxf(p1.x, g.x), 0.0f);
        float h1 = fmaxf(fminf(p1.w, g.w) - fmaxf(p1.y, g.y), 0.0f);
        float i1 = w1 * h1;
        float u1 = (ap1 + ag) - i1;
        bool  m1 = i1 * bu1 > bi1 * u1;
        bi1 = m1 ? i1 : bi1;
        bu1 = m1 ? u1 : bu1;
    }
    if (idx0 < N_PRED) ws_amax[idx0 * CHUNKS + c] = bi0 / bu0;
    if (idx1 < N_PRED) ws_amax[idx1 * CHUNKS + c] = bi1 / bu1;

    // fused passthrough (y==0 blocks reuse already-loaded preds)
    if (c == 0) {
        float4* out_pred = (float4*)out;
        if (idx0 < N_PRED) out_pred[idx0] = p0;
        if (idx1 < N_PRED) out_pred[idx1] = p1;
        if (blockIdx.x == 0) {
            float4* out_gt = (float4*)(out + 4 * N_PRED);
            for (int j = tid; j < N_GT; j += BLOCK) out_gt[j] = gt[j];
        }
    }
}

// --- phase 2: one wave per pred; grid 12500 x 256 ---------------------------
__global__ __launch_bounds__(BLOCK) void resolve(
        const float* __restrict__ ws_amax,
        const float4* __restrict__ pred, const float4* __restrict__ gt,
        float* __restrict__ out) {
#pragma clang fp contract(off)
    const int lane = threadIdx.x & 63;
    const int i    = (blockIdx.x * BLOCK + threadIdx.x) >> 6;  // pred id, < 50000
    float* out_max = out + 4 * N_PRED + 4 * N_GT;
    float* out_idx = out_max + N_PRED;

    const float4 p  = pred[i];
    const float  ap = (p.z - p.x) * (p.w - p.y);

    // chunk maxima: lanes 0..15 hold A_c; butterfly max -> amax on all lanes
    float av = (lane < CHUNKS) ? ws_amax[i * CHUNKS + lane] : 0.0f;
    float amax = av;
#pragma unroll
    for (int s = 1; s < 64; s <<= 1)
        amax = fmaxf(amax, __shfl_xor(amax, s));
    const float t = amax * TMARG;
    unsigned cmask = (unsigned)__ballot(lane < CHUNKS && av >= t);  // uniform

    float best = -1.0f;
    int   bidx = 0;
    while (cmask) {                         // wave-uniform scalar loop
        const int c = __builtin_ctz(cmask);
        cmask &= cmask - 1;
        const int cb = c * CHUNK;
#pragma unroll
        for (int s = 0; s < 2; ++s) {       // 125 gts = 64 + 61 lanes
            const int  o   = s * 64 + lane;
            const bool act = o < CHUNK;
            const int  j   = cb + (act ? o : 0);
            const float4 g  = gt[j];                       // coalesced, L1-hot
            const float  ag = (g.z - g.x) * (g.w - g.y);   // same fl expr as ref
            float w  = fmaxf(fminf(p.z, g.z) - fmaxf(p.x, g.x), 0.0f);
            float h  = fmaxf(fminf(p.w, g.w) - fmaxf(p.y, g.y), 0.0f);
            float in = w * h;
            float un = (ap + ag) - in;       // ref assoc order
            float q  = in / un;              // exact IEEE divide, every candidate
            if (act && q > best) { best = q; bidx = j; }   // per-lane ascending
        }
    }
    // lexicographic (q, -idx) reduce: max value, smallest index on ties
#pragma unroll
    for (int s = 1; s < 64; s <<= 1) {
        float oq = __shfl_xor(best, s);
        int   oi = __shfl_xor(bidx, s);
        if (oq > best || (oq == best && oi < bidx)) { best = oq; bidx = oi; }
    }
    if (lane == 0) { out_max[i] = best; out_idx[i] = (float)bidx; }
}

extern "C" void kernel_launch(void* const* d_in, const int* in_sizes, int n_in,
                              void* d_out, int out_size, void* d_ws, size_t ws_size,
                              hipStream_t stream) {
    const float4* pred = (const float4*)d_in[0];
    const float4* gt   = (const float4*)d_in[1];
    float* out = (float*)d_out;

    float* ws_amax = (float*)d_ws;  // 50000*16 floats = 3.2 MB, pred-major

    const int gx1 = (N_PRED + BLOCK * PPT - 1) / (BLOCK * PPT);  // 98
    chunk_max<<<dim3(gx1, CHUNKS), BLOCK, 0, stream>>>(pred, gt, ws_amax, out);

    const int gx2 = N_PRED / (BLOCK / 64);                       // 12500
    resolve<<<dim3(gx2), BLOCK, 0, stream>>>(ws_amax, pred, gt, out);
}